// Round 10
// baseline (504.315 us; speedup 1.0000x reference)
//
#include <hip/hip_runtime.h>

#define S_LEN  4096
#define DMODEL 2048
#define NHEADS 16
#define HDIM   128

typedef __bf16 bf16x8 __attribute__((ext_vector_type(8)));
typedef __bf16 bf16x2 __attribute__((ext_vector_type(2)));
typedef float  f32x4  __attribute__((ext_vector_type(4)));
typedef float  f32x16 __attribute__((ext_vector_type(16)));

__device__ __forceinline__ unsigned short f2b(float f) {
    unsigned int u = __float_as_uint(f);
    unsigned int r = (u + 0x7fffu + ((u >> 16) & 1u)) >> 16;
    return (unsigned short)r;
}

// pack two fp32 -> one dword of bf16 (lo = a, hi = b)
__device__ __forceinline__ unsigned int pkbf16(float a, float b) {
#if __has_builtin(__builtin_amdgcn_cvt_pk_bf16_f32)
    bf16x2 t = __builtin_amdgcn_cvt_pk_bf16_f32(a, b);
    return *(unsigned int*)&t;
#else
    return (unsigned int)f2b(a) | ((unsigned int)f2b(b) << 16);
#endif
}

__device__ __forceinline__ f32x4 mfma16(bf16x8 a, bf16x8 b, f32x4 c) {
    return __builtin_amdgcn_mfma_f32_16x16x32_bf16(a, b, c, 0, 0, 0);
}

__device__ __forceinline__ f32x16 mfma32(bf16x8 a, bf16x8 b, f32x16 c) {
    return __builtin_amdgcn_mfma_f32_32x32x16_bf16(a, b, c, 0, 0, 0);
}

// async global->LDS, 16B per lane; LDS dest = wave-uniform base + lane*16
__device__ __forceinline__ void ldg2lds16(const void* g, void* l) {
    __builtin_amdgcn_global_load_lds(
        (__attribute__((address_space(1))) void*)(void*)g,
        (__attribute__((address_space(3))) void*)l, 16, 0, 0);
}

// ---------------------------------------------------------------------------
// fp32 -> bf16 convert, single merged launch.
//   dst region xbv|Wqb|Wkb|Wvb|Wob is contiguous in the workspace: one flat
//   index covers all five tensors (x: 2M float4, each W: 1M float4).
// ---------------------------------------------------------------------------
__global__ __launch_bounds__(256) void cvt_all(
    const float* __restrict__ x,
    const float* __restrict__ w0, const float* __restrict__ w1,
    const float* __restrict__ w2, const float* __restrict__ w3,
    unsigned short* __restrict__ dst)
{
    int i = blockIdx.x * 256 + threadIdx.x;    // float4 index, 6M total
    const float* src; int off;
    if (i < (1 << 21)) { src = x; off = i; }
    else {
        int j = i - (1 << 21);
        int sel = j >> 20; off = j & ((1 << 20) - 1);
        src = (sel == 0) ? w0 : (sel == 1) ? w1 : (sel == 2) ? w2 : w3;
    }
    float4 v = ((const float4*)src)[off];
    uint2 h;
    h.x = pkbf16(v.x, v.y); h.y = pkbf16(v.z, v.w);
    ((uint2*)dst)[i] = h;
}

// ---------------------------------------------------------------------------
// m97-structure bf16 GEMM + T1 XCD swizzle.
//   z==2 (V) writes its output DIRECTLY TRANSPOSED to Vt[d][s]: the MFMA C
//   layout holds 4 consecutive m (=s) values per register quad, so each
//   (i,j) emits one packed 8B store. Eliminates the transpose_v kernel.
// ---------------------------------------------------------------------------
__global__ __launch_bounds__(256, 2) void gemm_qkv(
    const unsigned short* __restrict__ xb,
    const unsigned short* __restrict__ Wqb, const float* __restrict__ bq,
    const unsigned short* __restrict__ Wkb, const float* __restrict__ bk,
    const unsigned short* __restrict__ Wvb, const float* __restrict__ bv,
    unsigned short* __restrict__ Qb, unsigned short* __restrict__ Kb,
    unsigned short* __restrict__ Vt)
{
    // T1 swizzle: nwg = 16*32*3 = 1536 = 8 XCDs x 192.
    const int id  = blockIdx.x + 16 * (blockIdx.y + 32 * blockIdx.z);
    const int swz = (id & 7) * 192 + (id >> 3);
    const int n0 = (swz & 15) * 128;
    const int m0 = ((swz >> 4) & 31) * 128;
    const int z  = swz >> 9;

    const unsigned short* B = (z == 0) ? Wqb : (z == 1) ? Wkb : Wvb;
    const float* bias        = (z == 0) ? bq  : (z == 1) ? bk  : bv;
    const float oscale = (z == 0) ? 0.12751743f : 1.0f;  // log2(e)/sqrt(128)

    __shared__ alignas(16) unsigned short As[128 * 32];
    __shared__ alignas(16) unsigned short Bs[128 * 32];

    const int tid = threadIdx.x;
    const int w = tid >> 6, lane = tid & 63, lo = lane & 15, qd = lane >> 4;
    const int wm = (w >> 1) * 64, wn = (w & 1) * 64;
    const int rsel = lane >> 2, csel = (lane & 3) * 8;

    f32x4 acc[4][4] = {};

    for (int k0 = 0; k0 < DMODEL; k0 += 32) {
#pragma unroll
        for (int i = 0; i < 2; i++) {
            int c = w * 2 + i;
            ldg2lds16(&xb[(size_t)(m0 + c * 16 + rsel) * DMODEL + k0 + csel],
                      &As[c * 512]);
            ldg2lds16(&B [(size_t)(n0 + c * 16 + rsel) * DMODEL + k0 + csel],
                      &Bs[c * 512]);
        }
        __syncthreads();

        bf16x8 af[4], bfr[4];
#pragma unroll
        for (int i = 0; i < 4; i++)
            af[i] = *(const bf16x8*)&As[(wm + i * 16 + lo) * 32 + qd * 8];
#pragma unroll
        for (int j = 0; j < 4; j++)
            bfr[j] = *(const bf16x8*)&Bs[(wn + j * 16 + lo) * 32 + qd * 8];
#pragma unroll
        for (int i = 0; i < 4; i++)
#pragma unroll
            for (int j = 0; j < 4; j++)
                acc[i][j] = mfma16(af[i], bfr[j], acc[i][j]);
        __syncthreads();
    }

    if (z == 2) {
        // V: write transposed Vt[d=n][s=m]; r-quad is contiguous in m -> 8B store.
#pragma unroll
        for (int j = 0; j < 4; j++) {
            int n = n0 + wn + j * 16 + lo;
            float bv_ = bias[n];
#pragma unroll
            for (int i = 0; i < 4; i++) {
                int ms = m0 + wm + i * 16 + qd * 4;
                unsigned short tmp[4];
#pragma unroll
                for (int r = 0; r < 4; r++)
                    tmp[r] = f2b(acc[i][j][r] + bv_);
                *(uint2*)&Vt[(size_t)n * S_LEN + ms] = *(uint2*)tmp;
            }
        }
    } else {
        unsigned short* C = (z == 0) ? Qb : Kb;
#pragma unroll
        for (int j = 0; j < 4; j++) {
            int n = n0 + wn + j * 16 + lo;
            float bv_ = bias[n];
#pragma unroll
            for (int i = 0; i < 4; i++) {
#pragma unroll
                for (int r = 0; r < 4; r++) {
                    int m = m0 + wm + i * 16 + qd * 4 + r;
                    C[(size_t)m * DMODEL + n] = f2b((acc[i][j][r] + bv_) * oscale);
                }
            }
        }
    }
}

// Output projection variant: fp32 out + bias.
__global__ __launch_bounds__(256, 2) void gemm_out(
    const unsigned short* __restrict__ Aatt, const unsigned short* __restrict__ Wob,
    const float* __restrict__ bo, float* __restrict__ out)
{
    // T1 swizzle: nwg = 16*32 = 512 = 8 XCDs x 64.
    const int id  = blockIdx.x + 16 * blockIdx.y;
    const int swz = (id & 7) * 64 + (id >> 3);
    const int n0 = (swz & 15) * 128;
    const int m0 = (swz >> 4) * 128;

    __shared__ alignas(16) unsigned short As[128 * 32];
    __shared__ alignas(16) unsigned short Bs[128 * 32];

    const int tid = threadIdx.x;
    const int w = tid >> 6, lane = tid & 63, lo = lane & 15, qd = lane >> 4;
    const int wm = (w >> 1) * 64, wn = (w & 1) * 64;
    const int rsel = lane >> 2, csel = (lane & 3) * 8;

    f32x4 acc[4][4] = {};

    for (int k0 = 0; k0 < DMODEL; k0 += 32) {
#pragma unroll
        for (int i = 0; i < 2; i++) {
            int c = w * 2 + i;
            ldg2lds16(&Aatt[(size_t)(m0 + c * 16 + rsel) * DMODEL + k0 + csel],
                      &As[c * 512]);
            ldg2lds16(&Wob [(size_t)(n0 + c * 16 + rsel) * DMODEL + k0 + csel],
                      &Bs[c * 512]);
        }
        __syncthreads();

        bf16x8 af[4], bfr[4];
#pragma unroll
        for (int i = 0; i < 4; i++)
            af[i] = *(const bf16x8*)&As[(wm + i * 16 + lo) * 32 + qd * 8];
#pragma unroll
        for (int j = 0; j < 4; j++)
            bfr[j] = *(const bf16x8*)&Bs[(wn + j * 16 + lo) * 32 + qd * 8];
#pragma unroll
        for (int i = 0; i < 4; i++)
#pragma unroll
            for (int j = 0; j < 4; j++)
                acc[i][j] = mfma16(af[i], bfr[j], acc[i][j]);
        __syncthreads();
    }

#pragma unroll
    for (int j = 0; j < 4; j++) {
        int n = n0 + wn + j * 16 + lo;
        float bv_ = bo[n];
#pragma unroll
        for (int i = 0; i < 4; i++) {
#pragma unroll
            for (int r = 0; r < 4; r++) {
                int m = m0 + wm + i * 16 + qd * 4 + r;
                out[(size_t)m * DMODEL + n] = acc[i][j][r] + bv_;
            }
        }
    }
}

// ---------------------------------------------------------------------------
// Flash attention v12: v11 (T15 skew, +12%) + l-sum via MFMA ones-column.
//   v11 counters: VALU 48.6% > Mfma 38.5% -> VALU is the larger pipe. The
//   per-tile l-sum (14 adds + serial l_run chain) moves to the idle MFMA
//   pipe: o_l = mfma32(pa, ones) x2 per tile. o_l's C-layout rows match
//   o_acc's exactly -> epilogue shuffle-redistribution collapses to a
//   direct LDS-indexed merge.
// ---------------------------------------------------------------------------
__global__ __launch_bounds__(256, 2) void attn_kernel(
    const unsigned short* __restrict__ Qb, const unsigned short* __restrict__ Kb,
    const unsigned short* __restrict__ Vt, unsigned short* __restrict__ Ob)
{
    const int id = blockIdx.x;
    const int xcd = id & 7, slot = id >> 3;          // slot 0..127
    const int h  = (xcd << 1) | (slot >> 6);         // 2 heads per XCD
    const int q0 = (slot & 63) * 64;                 // 64-query block

    __shared__ alignas(16) unsigned char smem[65536];
    unsigned short* Ks0  = (unsigned short*)smem;            // [64][128] 16KB swz
    unsigned short* Ks1  = (unsigned short*)(smem + 16384);
    unsigned short* Vts0 = (unsigned short*)(smem + 32768);  // [128][64] 16KB swz
    unsigned short* Vts1 = (unsigned short*)(smem + 49152);
    float* Of = (float*)smem;                 // [2][32][128] 32KB (epilogue alias over Ks0/Ks1)
    float* Lf = (float*)(smem + 32768);       // epilogue alias over Vts0 (last read: step 63's SMPV)

    const int tid = threadIdx.x;
    const int w = tid >> 6, lane = tid & 63;
    const int qw = w >> 1, kw = w & 1;               // q-half / key-half of wave
    const int l31 = lane & 31, hi = lane >> 5;
    const int sw7 = l31 & 7;                          // row&7 for swizzled reads

    // Q fragments direct from global: lane's q row = q0 + qw*32 + l31.
    bf16x8 qf[8];
    {
        const unsigned short* qrow =
            &Qb[(size_t)(q0 + qw * 32 + l31) * DMODEL + h * HDIM];
#pragma unroll
        for (int sl = 0; sl < 8; sl++)
            qf[sl] = *(const bf16x8*)&qrow[sl * 16 + hi * 8];
    }

    // ones B-fragment for the l-sum MFMA (layout-independent: all-ones)
    bf16x8 onesb;
#pragma unroll
    for (int i = 0; i < 8; i++) onesb[i] = (__bf16)1.0f;

    f32x16 o_acc[4] = {};     // dt: d cols dt*32 + l31
    f32x16 o_l = {};          // l-sum accumulator (every col identical)

    const int krow = kw * 32 + l31;                   // A-row (key) for QK^T

#define STAGE_K(dst_, key0_)                                                  \
    {                                                                         \
        _Pragma("unroll")                                                     \
        for (int i = 0; i < 4; i++) {                                         \
            int r = w * 16 + i * 4 + (lane >> 4);                             \
            int c = (lane & 15) ^ (r & 7);                                    \
            ldg2lds16(&Kb[(size_t)((key0_) + r) * DMODEL + h * HDIM + c * 8], \
                      &(dst_)[(w * 16 + i * 4) * 128]);                       \
        }                                                                     \
    }
#define STAGE_V(dst_, key0_)                                                  \
    {                                                                         \
        _Pragma("unroll")                                                     \
        for (int i = 0; i < 4; i++) {                                         \
            int r = w * 32 + i * 8 + (lane >> 3);                             \
            int c = (lane & 7) ^ (r & 7);                                     \
            ldg2lds16(&Vt[(size_t)(h * HDIM + r) * S_LEN + (key0_) + c * 8],  \
                      &(dst_)[(w * 32 + i * 8) * 64]);                        \
        }                                                                     \
    }

    // QK^T of tile from KsC into SOUT (2 partial accumulators, chain depth 4).
#define QKT(KsC, SOUT)                                                        \
    {                                                                         \
        f32x16 sa_ = {}, sb_ = {};                                            \
        _Pragma("unroll")                                                     \
        for (int sl = 0; sl < 8; sl += 2) {                                   \
            bf16x8 kfa = *(const bf16x8*)                                     \
                &(KsC)[krow * 128 + (((2 * sl + hi) ^ sw7) * 8)];             \
            bf16x8 kfb = *(const bf16x8*)                                     \
                &(KsC)[krow * 128 + (((2 * (sl + 1) + hi) ^ sw7) * 8)];       \
            sa_ = mfma32(kfa, qf[sl], sa_);                                   \
            sb_ = mfma32(kfb, qf[sl + 1], sb_);                               \
        }                                                                     \
        SOUT = sa_ + sb_;                                                     \
    }

    // softmax of SIN + l-MFMA + PV from VtsP.
#define SMPV(SIN, VtsP)                                                       \
    {                                                                         \
        bf16x8 pa0, pa1;                                                      \
        _Pragma("unroll")                                                     \
        for (int k2 = 0; k2 < 2; k2++) {                                      \
            float e0 = __builtin_amdgcn_exp2f(SIN[8 * k2 + 0]);               \
            float e1 = __builtin_amdgcn_exp2f(SIN[8 * k2 + 1]);               \
            float e2 = __builtin_amdgcn_exp2f(SIN[8 * k2 + 2]);               \
            float e3 = __builtin_amdgcn_exp2f(SIN[8 * k2 + 3]);               \
            float e4 = __builtin_amdgcn_exp2f(SIN[8 * k2 + 4]);               \
            float e5 = __builtin_amdgcn_exp2f(SIN[8 * k2 + 5]);               \
            float e6 = __builtin_amdgcn_exp2f(SIN[8 * k2 + 6]);               \
            float e7 = __builtin_amdgcn_exp2f(SIN[8 * k2 + 7]);               \
            unsigned int c0 = pkbf16(e0, e1);                                 \
            unsigned int c1 = pkbf16(e2, e3);                                 \
            unsigned int c2 = pkbf16(e4, e5);                                 \
            unsigned int c3 = pkbf16(e6, e7);                                 \
            asm("v_permlane32_swap_b32 %0, %1" : "+v"(c0), "+v"(c2));         \
            asm("v_permlane32_swap_b32 %0, %1" : "+v"(c1), "+v"(c3));         \
            uint4 u; u.x = c0; u.y = c1; u.z = c2; u.w = c3;                  \
            if (k2 == 0) pa0 = *(bf16x8*)&u; else pa1 = *(bf16x8*)&u;         \
        }                                                                     \
        o_l = mfma32(pa0, onesb, o_l);                                        \
        o_l = mfma32(pa1, onesb, o_l);                                        \
        _Pragma("unroll")                                                     \
        for (int k2 = 0; k2 < 2; k2++) {                                      \
            const int gch = 4 * kw + 2 * k2 + hi;                             \
            bf16x8 pf = (k2 == 0) ? pa0 : pa1;                                \
            _Pragma("unroll")                                                 \
            for (int dt = 0; dt < 4; dt++) {                                  \
                bf16x8 vf = *(const bf16x8*)                                  \
                    &(VtsP)[(dt * 32 + l31) * 64 + ((gch ^ sw7) * 8)];        \
                o_acc[dt] = mfma32(pf, vf, o_acc[dt]);                        \
            }                                                                 \
        }                                                                     \
    }

    // One skewed step at tile t: stage K(t+1)->KN (guarded), stage V(t)->VC,
    // QK(t) from KC -> SOUT, softmax+PV of tile t-1 (SIN, VP), barrier.
#define ATTN_STEP(t_, KC, KN, VC, VP, SIN, SOUT)                              \
    {                                                                         \
        if ((t_) + 1 < S_LEN / 64) STAGE_K(KN, ((t_) + 1) * 64);              \
        STAGE_V(VC, (t_) * 64);                                               \
        __builtin_amdgcn_s_setprio(1);                                        \
        QKT(KC, SOUT);                                                        \
        SMPV(SIN, VP);                                                        \
        __builtin_amdgcn_s_setprio(0);                                        \
        __syncthreads();                                                      \
    }

    f32x16 sP, sQ;

    // prologue: K(0); drain; iter 0 (no softmax yet): stage K(1),V(0); QK(0).
    STAGE_K(Ks0, 0);
    __syncthreads();
    STAGE_K(Ks1, 64);
    STAGE_V(Vts0, 0);
    QKT(Ks0, sP);
    __syncthreads();                                  // drains K(1), V(0)

    // t = 1..62 in pairs (odd then even config), then t = 63.
    for (int t = 1; t < S_LEN / 64 - 1; t += 2) {
        ATTN_STEP(t,     Ks1, Ks0, Vts1, Vts0, sP, sQ);   // t odd
        ATTN_STEP(t + 1, Ks0, Ks1, Vts0, Vts1, sQ, sP);   // t+1 even
    }
    ATTN_STEP(S_LEN / 64 - 1, Ks1, Ks0, Vts1, Vts0, sP, sQ);  // t = 63 (odd)

    // final peel: softmax(63) + PV(63) from Vts1 (staged at t=63, drained).
    SMPV(sQ, Vts1);

#undef ATTN_STEP
#undef SMPV
#undef QKT
#undef STAGE_K
#undef STAGE_V

    // ---- epilogue: merge kw halves (O and l additive; no-max softmax) ----
    if (kw == 1) {
#pragma unroll
        for (int dt = 0; dt < 4; dt++)
#pragma unroll
            for (int r = 0; r < 16; r++) {
                int row = (r & 3) + 8 * (r >> 2) + 4 * hi;
                Of[(qw * 32 + row) * 128 + dt * 32 + l31] = o_acc[dt][r];
            }
    }
    // o_l columns are identical; 2 lanes (l31==0, hi=0/1) cover all 32 rows.
    if (l31 == 0) {
#pragma unroll
        for (int r = 0; r < 16; r++) {
            int row = (r & 3) + 8 * (r >> 2) + 4 * hi;
            Lf[(qw * 2 + kw) * 32 + row] = o_l[r];
        }
    }
    __syncthreads();

    if (kw == 0) {
        float linv[16];
#pragma unroll
        for (int r = 0; r < 16; r++) {
            int row = (r & 3) + 8 * (r >> 2) + 4 * hi;
            linv[r] = 1.0f / (Lf[(qw * 2 + 0) * 32 + row] +
                              Lf[(qw * 2 + 1) * 32 + row]);
        }
#pragma unroll
        for (int dt = 0; dt < 4; dt++)
#pragma unroll
            for (int r = 0; r < 16; r++) {
                int row = (r & 3) + 8 * (r >> 2) + 4 * hi;
                float v = o_acc[dt][r] + Of[(qw * 32 + row) * 128 + dt * 32 + l31];
                Ob[(size_t)(q0 + qw * 32 + row) * DMODEL + h * HDIM + dt * 32 + l31]
                    = f2b(v * linv[r]);
            }
    }
}

// ---------------------------------------------------------------------------
extern "C" void kernel_launch(void* const* d_in, const int* in_sizes, int n_in,
                              void* d_out, int out_size, void* d_ws, size_t ws_size,
                              hipStream_t stream)
{
    const float* x  = (const float*)d_in[0];
    const float* Wq = (const float*)d_in[1];
    const float* bq = (const float*)d_in[2];
    const float* Wk = (const float*)d_in[3];
    const float* bk = (const float*)d_in[4];
    const float* Wv = (const float*)d_in[5];
    const float* bv = (const float*)d_in[6];
    const float* Wo = (const float*)d_in[7];
    const float* bo = (const float*)d_in[8];
    float* out = (float*)d_out;

    const size_t N = (size_t)S_LEN * DMODEL;   // 8M elems
    const size_t W = (size_t)DMODEL * DMODEL;  // 4M elems
    unsigned short* Qb  = (unsigned short*)d_ws;
    unsigned short* Kb  = Qb + N;
    unsigned short* Vt  = Kb + N;    // V written TRANSPOSED here by gemm_qkv
    unsigned short* xbv = Vt + N;
    unsigned short* Wqb = xbv + N;
    unsigned short* Wkb = Wqb + W;
    unsigned short* Wvb = Wkb + W;
    unsigned short* Wob = Wvb + W;
    unsigned short* Ob  = xbv;       // alias: xbv dead after gemm_qkv

    // merged convert: x (2M float4) + 4 weights (1M float4 each), contiguous dst
    cvt_all<<<24576, 256, 0, stream>>>(x, Wq, Wk, Wv, Wo, xbv);

    gemm_qkv<<<dim3(DMODEL / 128, S_LEN / 128, 3), 256, 0, stream>>>(
        xbv, Wqb, bq, Wkb, bk, Wvb, bv, Qb, Kb, Vt);

    attn_kernel<<<1024, 256, 0, stream>>>(Qb, Kb, Vt, Ob);

    gemm_out<<<dim3(DMODEL / 128, S_LEN / 128), 256, 0, stream>>>(Ob, Wob, bo, out);
}

// Round 11
// 483.625 us; speedup vs baseline: 1.0428x; 1.0428x over previous
//
#include <hip/hip_runtime.h>

#define S_LEN  4096
#define DMODEL 2048
#define NHEADS 16
#define HDIM   128

typedef __bf16 bf16x8 __attribute__((ext_vector_type(8)));
typedef __bf16 bf16x2 __attribute__((ext_vector_type(2)));
typedef float  f32x4  __attribute__((ext_vector_type(4)));
typedef float  f32x16 __attribute__((ext_vector_type(16)));

__device__ __forceinline__ unsigned short f2b(float f) {
    unsigned int u = __float_as_uint(f);
    unsigned int r = (u + 0x7fffu + ((u >> 16) & 1u)) >> 16;
    return (unsigned short)r;
}

// pack two fp32 -> one dword of bf16 (lo = a, hi = b)
__device__ __forceinline__ unsigned int pkbf16(float a, float b) {
#if __has_builtin(__builtin_amdgcn_cvt_pk_bf16_f32)
    bf16x2 t = __builtin_amdgcn_cvt_pk_bf16_f32(a, b);
    return *(unsigned int*)&t;
#else
    return (unsigned int)f2b(a) | ((unsigned int)f2b(b) << 16);
#endif
}

__device__ __forceinline__ f32x4 mfma16(bf16x8 a, bf16x8 b, f32x4 c) {
    return __builtin_amdgcn_mfma_f32_16x16x32_bf16(a, b, c, 0, 0, 0);
}

__device__ __forceinline__ f32x16 mfma32(bf16x8 a, bf16x8 b, f32x16 c) {
    return __builtin_amdgcn_mfma_f32_32x32x16_bf16(a, b, c, 0, 0, 0);
}

// async global->LDS, 16B per lane; LDS dest = wave-uniform base + lane*16
__device__ __forceinline__ void ldg2lds16(const void* g, void* l) {
    __builtin_amdgcn_global_load_lds(
        (__attribute__((address_space(1))) void*)(void*)g,
        (__attribute__((address_space(3))) void*)l, 16, 0, 0);
}

// ---------------------------------------------------------------------------
// fp32 -> bf16 convert, single merged launch.
//   dst region xbv|Wqb|Wkb|Wvb|Wob is contiguous in the workspace: one flat
//   index covers all five tensors (x: 2M float4, each W: 1M float4).
// ---------------------------------------------------------------------------
__global__ __launch_bounds__(256) void cvt_all(
    const float* __restrict__ x,
    const float* __restrict__ w0, const float* __restrict__ w1,
    const float* __restrict__ w2, const float* __restrict__ w3,
    unsigned short* __restrict__ dst)
{
    int i = blockIdx.x * 256 + threadIdx.x;    // float4 index, 6M total
    const float* src; int off;
    if (i < (1 << 21)) { src = x; off = i; }
    else {
        int j = i - (1 << 21);
        int sel = j >> 20; off = j & ((1 << 20) - 1);
        src = (sel == 0) ? w0 : (sel == 1) ? w1 : (sel == 2) ? w2 : w3;
    }
    float4 v = ((const float4*)src)[off];
    uint2 h;
    h.x = pkbf16(v.x, v.y); h.y = pkbf16(v.z, v.w);
    ((uint2*)dst)[i] = h;
}

// ---------------------------------------------------------------------------
// m97-structure bf16 GEMM + T1 XCD swizzle (accepted plateau config).
// ---------------------------------------------------------------------------
__global__ __launch_bounds__(256, 2) void gemm_qkv(
    const unsigned short* __restrict__ xb,
    const unsigned short* __restrict__ Wqb, const float* __restrict__ bq,
    const unsigned short* __restrict__ Wkb, const float* __restrict__ bk,
    const unsigned short* __restrict__ Wvb, const float* __restrict__ bv,
    unsigned short* __restrict__ Qb, unsigned short* __restrict__ Kb,
    unsigned short* __restrict__ Vb)
{
    // T1 swizzle: nwg = 16*32*3 = 1536 = 8 XCDs x 192.
    const int id  = blockIdx.x + 16 * (blockIdx.y + 32 * blockIdx.z);
    const int swz = (id & 7) * 192 + (id >> 3);
    const int n0 = (swz & 15) * 128;
    const int m0 = ((swz >> 4) & 31) * 128;
    const int z  = swz >> 9;

    const unsigned short* B = (z == 0) ? Wqb : (z == 1) ? Wkb : Wvb;
    const float* bias        = (z == 0) ? bq  : (z == 1) ? bk  : bv;
    unsigned short* C        = (z == 0) ? Qb  : (z == 1) ? Kb  : Vb;
    const float oscale = (z == 0) ? 0.12751743f : 1.0f;  // log2(e)/sqrt(128)

    __shared__ alignas(16) unsigned short As[128 * 32];
    __shared__ alignas(16) unsigned short Bs[128 * 32];

    const int tid = threadIdx.x;
    const int w = tid >> 6, lane = tid & 63, lo = lane & 15, qd = lane >> 4;
    const int wm = (w >> 1) * 64, wn = (w & 1) * 64;
    const int rsel = lane >> 2, csel = (lane & 3) * 8;

    f32x4 acc[4][4] = {};

    for (int k0 = 0; k0 < DMODEL; k0 += 32) {
#pragma unroll
        for (int i = 0; i < 2; i++) {
            int c = w * 2 + i;
            ldg2lds16(&xb[(size_t)(m0 + c * 16 + rsel) * DMODEL + k0 + csel],
                      &As[c * 512]);
            ldg2lds16(&B [(size_t)(n0 + c * 16 + rsel) * DMODEL + k0 + csel],
                      &Bs[c * 512]);
        }
        __syncthreads();

        bf16x8 af[4], bfr[4];
#pragma unroll
        for (int i = 0; i < 4; i++)
            af[i] = *(const bf16x8*)&As[(wm + i * 16 + lo) * 32 + qd * 8];
#pragma unroll
        for (int j = 0; j < 4; j++)
            bfr[j] = *(const bf16x8*)&Bs[(wn + j * 16 + lo) * 32 + qd * 8];
#pragma unroll
        for (int i = 0; i < 4; i++)
#pragma unroll
            for (int j = 0; j < 4; j++)
                acc[i][j] = mfma16(af[i], bfr[j], acc[i][j]);
        __syncthreads();
    }

#pragma unroll
    for (int j = 0; j < 4; j++) {
        int n = n0 + wn + j * 16 + lo;
        float bv_ = bias[n];
#pragma unroll
        for (int i = 0; i < 4; i++) {
#pragma unroll
            for (int r = 0; r < 4; r++) {
                int m = m0 + wm + i * 16 + qd * 4 + r;
                C[(size_t)m * DMODEL + n] = f2b((acc[i][j][r] + bv_) * oscale);
            }
        }
    }
}

// Output projection variant: fp32 out + bias.
__global__ __launch_bounds__(256, 2) void gemm_out(
    const unsigned short* __restrict__ Aatt, const unsigned short* __restrict__ Wob,
    const float* __restrict__ bo, float* __restrict__ out)
{
    // T1 swizzle: nwg = 16*32 = 512 = 8 XCDs x 64.
    const int id  = blockIdx.x + 16 * blockIdx.y;
    const int swz = (id & 7) * 64 + (id >> 3);
    const int n0 = (swz & 15) * 128;
    const int m0 = (swz >> 4) * 128;

    __shared__ alignas(16) unsigned short As[128 * 32];
    __shared__ alignas(16) unsigned short Bs[128 * 32];

    const int tid = threadIdx.x;
    const int w = tid >> 6, lane = tid & 63, lo = lane & 15, qd = lane >> 4;
    const int wm = (w >> 1) * 64, wn = (w & 1) * 64;
    const int rsel = lane >> 2, csel = (lane & 3) * 8;

    f32x4 acc[4][4] = {};

    for (int k0 = 0; k0 < DMODEL; k0 += 32) {
#pragma unroll
        for (int i = 0; i < 2; i++) {
            int c = w * 2 + i;
            ldg2lds16(&Aatt[(size_t)(m0 + c * 16 + rsel) * DMODEL + k0 + csel],
                      &As[c * 512]);
            ldg2lds16(&Wob [(size_t)(n0 + c * 16 + rsel) * DMODEL + k0 + csel],
                      &Bs[c * 512]);
        }
        __syncthreads();

        bf16x8 af[4], bfr[4];
#pragma unroll
        for (int i = 0; i < 4; i++)
            af[i] = *(const bf16x8*)&As[(wm + i * 16 + lo) * 32 + qd * 8];
#pragma unroll
        for (int j = 0; j < 4; j++)
            bfr[j] = *(const bf16x8*)&Bs[(wn + j * 16 + lo) * 32 + qd * 8];
#pragma unroll
        for (int i = 0; i < 4; i++)
#pragma unroll
            for (int j = 0; j < 4; j++)
                acc[i][j] = mfma16(af[i], bfr[j], acc[i][j]);
        __syncthreads();
    }

#pragma unroll
    for (int j = 0; j < 4; j++) {
        int n = n0 + wn + j * 16 + lo;
        float bv_ = bo[n];
#pragma unroll
        for (int i = 0; i < 4; i++) {
#pragma unroll
            for (int r = 0; r < 4; r++) {
                int m = m0 + wm + i * 16 + qd * 4 + r;
                out[(size_t)m * DMODEL + n] = acc[i][j][r] + bv_;
            }
        }
    }
}

// ---------------------------------------------------------------------------
// V transpose: Vb [s][n] -> Vt [n][s]
// ---------------------------------------------------------------------------
__global__ __launch_bounds__(256) void transpose_v(
    const unsigned short* __restrict__ Vb, unsigned short* __restrict__ Vt)
{
    __shared__ unsigned short tile[64 * 67];
    const int s0 = blockIdx.x * 64;
    const int d0 = blockIdx.y * 64;
    const int tid = threadIdx.x;
#pragma unroll
    for (int i = 0; i < 2; i++) {
        int chunk = tid + i * 256;
        int r = chunk >> 3, c8 = (chunk & 7) * 8;
        uint4 v = *(const uint4*)&Vb[(size_t)(s0 + r) * DMODEL + d0 + c8];
        const unsigned short* p = (const unsigned short*)&v;
#pragma unroll
        for (int j = 0; j < 8; j++) tile[r * 67 + c8 + j] = p[j];
    }
    __syncthreads();
#pragma unroll
    for (int i = 0; i < 2; i++) {
        int chunk = tid + i * 256;
        int r = chunk >> 3, c8 = (chunk & 7) * 8;
        unsigned short tmp[8];
#pragma unroll
        for (int j = 0; j < 8; j++) tmp[j] = tile[(c8 + j) * 67 + r];
        *(uint4*)&Vt[(size_t)(d0 + r) * S_LEN + s0 + c8] = *(uint4*)tmp;
    }
}

// ---------------------------------------------------------------------------
// Flash attention v11 (RESTORED — session best, 167.7 us in R9).
//   R10 post-mortem: moving the l-sum to MFMA (+2 mfma32/tile) cost +10.7%
//   time (+12.5% on the serial MFMA stream, near-1:1) — in the T15-skewed
//   structure, softmax VALU is already hidden under QK MFMA; MFMA is the
//   critical pipe. l-sum stays on VALU; epilogue uses shuffle redistribution.
// ---------------------------------------------------------------------------
__global__ __launch_bounds__(256, 2) void attn_kernel(
    const unsigned short* __restrict__ Qb, const unsigned short* __restrict__ Kb,
    const unsigned short* __restrict__ Vt, unsigned short* __restrict__ Ob)
{
    const int id = blockIdx.x;
    const int xcd = id & 7, slot = id >> 3;          // slot 0..127
    const int h  = (xcd << 1) | (slot >> 6);         // 2 heads per XCD
    const int q0 = (slot & 63) * 64;                 // 64-query block

    __shared__ alignas(16) unsigned char smem[65536];
    unsigned short* Ks0  = (unsigned short*)smem;            // [64][128] 16KB swz
    unsigned short* Ks1  = (unsigned short*)(smem + 16384);
    unsigned short* Vts0 = (unsigned short*)(smem + 32768);  // [128][64] 16KB swz
    unsigned short* Vts1 = (unsigned short*)(smem + 49152);
    float* Of = (float*)smem;                 // [2][32][128] 32KB (epilogue alias over Ks0/Ks1)
    float* Lf = (float*)(smem + 32768);       // epilogue alias over Vts0 (last read: PV(62))

    const int tid = threadIdx.x;
    const int w = tid >> 6, lane = tid & 63;
    const int qw = w >> 1, kw = w & 1;               // q-half / key-half of wave
    const int l31 = lane & 31, hi = lane >> 5;
    const int sw7 = l31 & 7;                          // row&7 for swizzled reads

    // Q fragments direct from global: lane's q row = q0 + qw*32 + l31.
    bf16x8 qf[8];
    {
        const unsigned short* qrow =
            &Qb[(size_t)(q0 + qw * 32 + l31) * DMODEL + h * HDIM];
#pragma unroll
        for (int sl = 0; sl < 8; sl++)
            qf[sl] = *(const bf16x8*)&qrow[sl * 16 + hi * 8];
    }

    f32x16 o_acc[4] = {};     // dt: d cols dt*32 + l31
    float l_run = 0.f;

    const int krow = kw * 32 + l31;                   // A-row (key) for QK^T

#define STAGE_K(dst_, key0_)                                                  \
    {                                                                         \
        _Pragma("unroll")                                                     \
        for (int i = 0; i < 4; i++) {                                         \
            int r = w * 16 + i * 4 + (lane >> 4);                             \
            int c = (lane & 15) ^ (r & 7);                                    \
            ldg2lds16(&Kb[(size_t)((key0_) + r) * DMODEL + h * HDIM + c * 8], \
                      &(dst_)[(w * 16 + i * 4) * 128]);                       \
        }                                                                     \
    }
#define STAGE_V(dst_, key0_)                                                  \
    {                                                                         \
        _Pragma("unroll")                                                     \
        for (int i = 0; i < 4; i++) {                                         \
            int r = w * 32 + i * 8 + (lane >> 3);                             \
            int c = (lane & 7) ^ (r & 7);                                     \
            ldg2lds16(&Vt[(size_t)(h * HDIM + r) * S_LEN + (key0_) + c * 8],  \
                      &(dst_)[(w * 32 + i * 8) * 64]);                        \
        }                                                                     \
    }

    // QK^T of tile from KsC into SOUT (2 partial accumulators, chain depth 4).
#define QKT(KsC, SOUT)                                                        \
    {                                                                         \
        f32x16 sa_ = {}, sb_ = {};                                            \
        _Pragma("unroll")                                                     \
        for (int sl = 0; sl < 8; sl += 2) {                                   \
            bf16x8 kfa = *(const bf16x8*)                                     \
                &(KsC)[krow * 128 + (((2 * sl + hi) ^ sw7) * 8)];             \
            bf16x8 kfb = *(const bf16x8*)                                     \
                &(KsC)[krow * 128 + (((2 * (sl + 1) + hi) ^ sw7) * 8)];       \
            sa_ = mfma32(kfa, qf[sl], sa_);                                   \
            sb_ = mfma32(kfb, qf[sl + 1], sb_);                               \
        }                                                                     \
        SOUT = sa_ + sb_;                                                     \
    }

    // softmax of SIN + PV from VtsP.
#define SMPV(SIN, VtsP)                                                       \
    {                                                                         \
        bf16x8 pa0, pa1;                                                      \
        float ls = 0.f;                                                       \
        _Pragma("unroll")                                                     \
        for (int k2 = 0; k2 < 2; k2++) {                                      \
            float e0 = __builtin_amdgcn_exp2f(SIN[8 * k2 + 0]);               \
            float e1 = __builtin_amdgcn_exp2f(SIN[8 * k2 + 1]);               \
            float e2 = __builtin_amdgcn_exp2f(SIN[8 * k2 + 2]);               \
            float e3 = __builtin_amdgcn_exp2f(SIN[8 * k2 + 3]);               \
            float e4 = __builtin_amdgcn_exp2f(SIN[8 * k2 + 4]);               \
            float e5 = __builtin_amdgcn_exp2f(SIN[8 * k2 + 5]);               \
            float e6 = __builtin_amdgcn_exp2f(SIN[8 * k2 + 6]);               \
            float e7 = __builtin_amdgcn_exp2f(SIN[8 * k2 + 7]);               \
            ls += ((e0 + e1) + (e2 + e3)) + ((e4 + e5) + (e6 + e7));          \
            unsigned int c0 = pkbf16(e0, e1);                                 \
            unsigned int c1 = pkbf16(e2, e3);                                 \
            unsigned int c2 = pkbf16(e4, e5);                                 \
            unsigned int c3 = pkbf16(e6, e7);                                 \
            asm("v_permlane32_swap_b32 %0, %1" : "+v"(c0), "+v"(c2));         \
            asm("v_permlane32_swap_b32 %0, %1" : "+v"(c1), "+v"(c3));         \
            uint4 u; u.x = c0; u.y = c1; u.z = c2; u.w = c3;                  \
            if (k2 == 0) pa0 = *(bf16x8*)&u; else pa1 = *(bf16x8*)&u;         \
        }                                                                     \
        l_run += ls;                                                          \
        _Pragma("unroll")                                                     \
        for (int k2 = 0; k2 < 2; k2++) {                                      \
            const int gch = 4 * kw + 2 * k2 + hi;                             \
            bf16x8 pf = (k2 == 0) ? pa0 : pa1;                                \
            _Pragma("unroll")                                                 \
            for (int dt = 0; dt < 4; dt++) {                                  \
                bf16x8 vf = *(const bf16x8*)                                  \
                    &(VtsP)[(dt * 32 + l31) * 64 + ((gch ^ sw7) * 8)];        \
                o_acc[dt] = mfma32(pf, vf, o_acc[dt]);                        \
            }                                                                 \
        }                                                                     \
    }

    // One skewed step at tile t: stage K(t+1)->KN (guarded), stage V(t)->VC,
    // QK(t) from KC -> SOUT, softmax+PV of tile t-1 (SIN, VP), barrier.
#define ATTN_STEP(t_, KC, KN, VC, VP, SIN, SOUT)                              \
    {                                                                         \
        if ((t_) + 1 < S_LEN / 64) STAGE_K(KN, ((t_) + 1) * 64);              \
        STAGE_V(VC, (t_) * 64);                                               \
        __builtin_amdgcn_s_setprio(1);                                        \
        QKT(KC, SOUT);                                                        \
        SMPV(SIN, VP);                                                        \
        __builtin_amdgcn_s_setprio(0);                                        \
        __syncthreads();                                                      \
    }

    f32x16 sP, sQ;

    // prologue: K(0); drain; iter 0 (no softmax yet): stage K(1),V(0); QK(0).
    STAGE_K(Ks0, 0);
    __syncthreads();
    STAGE_K(Ks1, 64);
    STAGE_V(Vts0, 0);
    QKT(Ks0, sP);
    __syncthreads();                                  // drains K(1), V(0)

    // t = 1..62 in pairs (odd then even config), then t = 63.
    for (int t = 1; t < S_LEN / 64 - 1; t += 2) {
        ATTN_STEP(t,     Ks1, Ks0, Vts1, Vts0, sP, sQ);   // t odd
        ATTN_STEP(t + 1, Ks0, Ks1, Vts0, Vts1, sQ, sP);   // t+1 even
    }
    ATTN_STEP(S_LEN / 64 - 1, Ks1, Ks0, Vts1, Vts0, sP, sQ);  // t = 63 (odd)

    // final peel: softmax(63) + PV(63) from Vts1 (staged at t=63, drained).
    SMPV(sQ, Vts1);

#undef ATTN_STEP
#undef SMPV
#undef QKT
#undef STAGE_K
#undef STAGE_V

    // ---- epilogue: merge kw halves (O and l additive; no-max softmax) ----
    float l = l_run + __shfl_xor(l_run, 32);   // full 32-key half per lane's q

    if (kw == 1) {
#pragma unroll
        for (int dt = 0; dt < 4; dt++)
#pragma unroll
            for (int r = 0; r < 16; r++) {
                int row = (r & 3) + 8 * (r >> 2) + 4 * hi;
                Of[(qw * 32 + row) * 128 + dt * 32 + l31] = o_acc[dt][r];
            }
    }
    if (hi == 0) Lf[(qw * 2 + kw) * 32 + l31] = l;
    __syncthreads();

    if (kw == 0) {
        float linv[16];
#pragma unroll
        for (int r = 0; r < 16; r++) {
            int row = (r & 3) + 8 * (r >> 2) + 4 * hi;
            linv[r] = 1.0f / (Lf[(qw * 2 + 0) * 32 + row] +
                              Lf[(qw * 2 + 1) * 32 + row]);
        }
#pragma unroll
        for (int dt = 0; dt < 4; dt++)
#pragma unroll
            for (int r = 0; r < 16; r++) {
                int row = (r & 3) + 8 * (r >> 2) + 4 * hi;
                float v = o_acc[dt][r] + Of[(qw * 32 + row) * 128 + dt * 32 + l31];
                Ob[(size_t)(q0 + qw * 32 + row) * DMODEL + h * HDIM + dt * 32 + l31]
                    = f2b(v * linv[r]);
            }
    }
}

// ---------------------------------------------------------------------------
extern "C" void kernel_launch(void* const* d_in, const int* in_sizes, int n_in,
                              void* d_out, int out_size, void* d_ws, size_t ws_size,
                              hipStream_t stream)
{
    const float* x  = (const float*)d_in[0];
    const float* Wq = (const float*)d_in[1];
    const float* bq = (const float*)d_in[2];
    const float* Wk = (const float*)d_in[3];
    const float* bk = (const float*)d_in[4];
    const float* Wv = (const float*)d_in[5];
    const float* bv = (const float*)d_in[6];
    const float* Wo = (const float*)d_in[7];
    const float* bo = (const float*)d_in[8];
    float* out = (float*)d_out;

    const size_t N = (size_t)S_LEN * DMODEL;   // 8M elems
    const size_t W = (size_t)DMODEL * DMODEL;  // 4M elems
    unsigned short* Qb  = (unsigned short*)d_ws;
    unsigned short* Kb  = Qb + N;
    unsigned short* Vb  = Kb + N;
    unsigned short* xbv = Vb + N;
    unsigned short* Wqb = xbv + N;
    unsigned short* Wkb = Wqb + W;
    unsigned short* Wvb = Wkb + W;
    unsigned short* Wob = Wvb + W;
    unsigned short* Vt  = xbv;   // alias after gemm_qkv
    unsigned short* Ob  = Vb;    // alias after transpose

    // merged convert: x (2M float4) + 4 weights (1M float4 each), contiguous dst
    cvt_all<<<24576, 256, 0, stream>>>(x, Wq, Wk, Wv, Wo, xbv);

    gemm_qkv<<<dim3(DMODEL / 128, S_LEN / 128, 3), 256, 0, stream>>>(
        xbv, Wqb, bq, Wkb, bk, Wvb, bv, Qb, Kb, Vb);

    transpose_v<<<dim3(S_LEN / 64, DMODEL / 64), 256, 0, stream>>>(Vb, Vt);

    attn_kernel<<<1024, 256, 0, stream>>>(Qb, Kb, Vt, Ob);

    gemm_out<<<dim3(DMODEL / 128, S_LEN / 128), 256, 0, stream>>>(Ob, Wob, bo, out);
}